// Round 5
// baseline (990.821 us; speedup 1.0000x reference)
//
#include <hip/hip_runtime.h>

#define B_ 4
#define H_ 256
#define W_ 256
#define PXF4 9   // float4 per pixel: 8 data + 1 pad (144 B stride, 16-B aligned, conflict-free)

// f32 dot of 32-register array vs one f32 LDS pixel row (direct LDS pointer form, P=1 fallback)
// NOTE: numerics-load-bearing — do not change accumulation structure (absmax 12.625 verified).
__device__ __forceinline__ float dot32f(const float* a, const float4* r) {
    float s0 = 0.f, s1 = 0.f, s2 = 0.f, s3 = 0.f;
#pragma unroll
    for (int u = 0; u < 8; ++u) {
        float4 q = r[u];
        s0 += a[4*u+0] * q.x; s1 += a[4*u+1] * q.y;
        s2 += a[4*u+2] * q.z; s3 += a[4*u+3] * q.w;
    }
    return (s0 + s1) + (s2 + s3);
}

// Same accumulation structure, operand pre-staged in registers (shared between 2 pixels).
__device__ __forceinline__ float dot32q(const float* a, const float4* q) {
    float s0 = 0.f, s1 = 0.f, s2 = 0.f, s3 = 0.f;
#pragma unroll
    for (int u = 0; u < 8; ++u) {
        float4 v = q[u];
        s0 += a[4*u+0] * v.x; s1 += a[4*u+1] * v.y;
        s2 += a[4*u+2] * v.z; s3 += a[4*u+3] * v.w;
    }
    return (s0 + s1) + (s2 + s3);
}

// ============================================================================
// P=2 kernel: each thread owns two vertically adjacent pixels (rows 2ty, 2ty+1).
// The 9x10 union neighborhood is swept once; each staged 128-B pixel row feeds
// TWO dots -> LDS read traffic per pixel drops 81->45 batches (1.8x less).
// Per-pixel FP op order is identical to the P=1 kernel (bit-identical output).
// ============================================================================
template<int TSX, int TSYH, int NTH>
__global__ void __launch_bounds__(NTH, 1)   // 1 wave/SIMD min: LDS caps us there anyway; frees VGPRs
gocor2(const float* __restrict__ rf_g,
       const float* __restrict__ beta_p, const float* __restrict__ tw_p,
       const float* __restrict__ sw_p,  const float* __restrict__ mw_p,
       const float* __restrict__ mrw_p, const float* __restrict__ mrb_p,
       const float* __restrict__ lrw_p, const float* __restrict__ lrb_p,
       const float* __restrict__ wreg_p, const float* __restrict__ lsl_p,
       float* __restrict__ out)
{
    constexpr int TWXc = TSX + 8, TWYc = 2*TSYH + 8, NPXc = TWXc * TWYc;
    extern __shared__ float4 smem[];
    float4* s_rf  = smem;                    // NPXc * PXF4
    float4* s_kp  = smem + NPXc * PXF4;      // 81   {A0, A1, Y, -}
    float*  s_bias = (float*)(s_kp + 81);    // [0..32) mr_b, [32..64) lr_b

    const int tid = threadIdx.x;
    const int tx = tid % TSX, ty = tid / TSX;
    const int ty2 = 2 * ty;
    const int bx = blockIdx.x * TSX, by = blockIdx.y * (2*TSYH), bb = blockIdx.z;
    const float* rfb = rf_g + (size_t)bb * H_ * W_ * 32;

    // ---- stage f32 rf tile (+halo), zero outside image ----
    for (int idx = tid; idx < NPXc * 8; idx += NTH) {
        int u = idx & 7, p = idx >> 3;
        int ly = p / TWXc, lx = p - ly * TWXc;
        int gy = by + ly - 4, gx = bx + lx - 4;
        float4 v = make_float4(0.f, 0.f, 0.f, 0.f);
        if (gy >= 0 && gy < H_ && gx >= 0 && gx < W_)
            v = *(const float4*)(rfb + ((size_t)(gy * W_ + gx)) * 32 + u * 4);
        s_rf[p * PXF4 + u] = v;
    }

    // ---- per-block activation params (f32, faithful to reference) ----
    if (tid < 81) {
        int i = tid / 9, j = tid % 9;
        float di = (float)(i - 4), dj = (float)(j - 4);
        float dist = sqrtf(di * di + dj * dj);
        float y = 0.f, vp = 0.f, m = 0.f;
        for (int b = 0; b < 10; ++b) {
            float bd = 2.f * dist - (float)b;
            float val;
            if (i < 8) val = fmaxf(0.f, 1.f - fabsf(bd));        // triangular rows 0..7
            else       val = fminf(1.f, fmaxf(0.f, 1.f + bd));   // clipped row 8 (faithful)
            y  += val * tw_p[b];
            vp += val * sw_p[b];
            m  += val * mw_p[b];
        }
        float wm = 1.f / (1.f + expf(-m));
        s_kp[tid] = make_float4(vp * 0.5f * (1.f - wm),   // A0 = vp*(1-a)/2
                                vp * 0.5f * (1.f + wm),   // A1 = vp*(1+a)/2
                                vp * y, 0.f);             // Y  = vp*y
    }
    if (tid < 32)      s_bias[tid] = mrb_p[tid];
    else if (tid < 64) s_bias[tid] = lrb_p[tid - 32];

    float beta = beta_p[0];
    float wr   = wreg_p[0];
    float regw = fmaxf(wr * wr, (1e-5f * 1e-5f) / (32.f * 32.f));
    float step = expf(lsl_p[0]);

    __syncthreads();

    // ---- init: w = beta * rf / (mean(rf^2) + 1e-6) for both owned pixels ----
    float w0[32], w1[32];
    {
        const float4* r0 = &s_rf[(((ty2 + 4) * TWXc) + (tx + 4)) * PXF4];
        const float4* r1 = &s_rf[(((ty2 + 5) * TWXc) + (tx + 4)) * PXF4];
#pragma unroll
        for (int u = 0; u < 8; ++u) {
            float4 q0 = r0[u], q1 = r1[u];
            w0[4*u+0] = q0.x; w0[4*u+1] = q0.y; w0[4*u+2] = q0.z; w0[4*u+3] = q0.w;
            w1[4*u+0] = q1.x; w1[4*u+1] = q1.y; w1[4*u+2] = q1.z; w1[4*u+3] = q1.w;
        }
        float m0 = 0.f, m1 = 0.f;
#pragma unroll
        for (int c = 0; c < 32; ++c) { m0 += w0[c] * w0[c]; m1 += w1[c] * w1[c]; }
        float i0 = beta / (m0 * (1.f / 32.f) + 1e-6f);
        float i1 = beta / (m1 * (1.f / 32.f) + 1e-6f);
#pragma unroll
        for (int c = 0; c < 32; ++c) { w0[c] *= i0; w1[c] *= i1; }
    }

    float mp0[32], mp1[32], fg0[32], fg1[32];

    // staged-quad loader; rowbase is read from the enclosing scope
#define LOADQ(Q, JJ) do { const float4* _r = &s_rf[(rowbase + (JJ)) * PXF4]; \
    _Pragma("unroll") for (int _u = 0; _u < 8; ++_u) (Q)[_u] = _r[_u]; } while (0)

    for (int it = 0; it < 3; ++it) {
        unsigned long long spa0 = 0ull, sna0 = 0ull, spb0 = 0ull, snb0 = 0ull;
        unsigned int spa1 = 0u, sna1 = 0u, spb1 = 0u, snb1 = 0u;

        // ---- Phase A: c_k -> s = dact*res; mapped = s @ mr_w + mr_b; record sign(c_k) ----
        auto bodyA = [&](int k, const float4* q, const float* w, float* mp,
                         unsigned long long& sp0, unsigned long long& sn0,
                         unsigned int& sp1, unsigned int& sn1) {
            float ck = dot32q(w, q) * (1.f / 32.f);
            if (ck > 0.f)      { if (k < 64) sp0 |= 1ull << k; else sp1 |= 1u << (k - 64); }
            else if (ck < 0.f) { if (k < 64) sn0 |= 1ull << k; else sn1 |= 1u << (k - 64); }
            float4 kp = s_kp[k];
            float sg = (ck > 0.f) ? 1.f : ((ck < 0.f) ? -1.f : 0.f);
            float act  = kp.x * fabsf(ck) + kp.y * ck;
            float res  = act - kp.z;
            float dact = kp.x * sg + kp.y;
            float s = dact * res;
            const float* mr = mrw_p + k * 32;    // wave-uniform -> s_load, K$-hot
#pragma unroll
            for (int c = 0; c < 32; ++c) mp[c] += s * mr[c];
        };
#pragma unroll
        for (int c = 0; c < 32; ++c) { mp0[c] = s_bias[c]; mp1[c] = s_bias[c]; }
#pragma unroll 1
        for (int dy = 0; dy < 10; ++dy) {        // pixel0: i = dy (dy<9); pixel1: i = dy-1 (dy>0)
            const int rowbase = (ty2 + dy) * TWXc + tx;
            float4 qa[8], qb[8];
            LOADQ(qa, 0);
#pragma unroll 1
            for (int j = 0; j < 8; j += 2) {     // double-buffered: loads issue 1 batch ahead
                LOADQ(qb, j + 1);
                if (dy < 9) bodyA(dy*9 + j,       qa, w0, mp0, spa0, sna0, spa1, sna1);
                if (dy > 0) bodyA((dy-1)*9 + j,   qa, w1, mp1, spb0, snb0, spb1, snb1);
                LOADQ(qa, j + 2);
                if (dy < 9) bodyA(dy*9 + j+1,     qb, w0, mp0, spa0, sna0, spa1, sna1);
                if (dy > 0) bodyA((dy-1)*9 + j+1, qb, w1, mp1, spb0, snb0, spb1, snb1);
            }
            if (dy < 9) bodyA(dy*9 + 8,       qa, w0, mp0, spa0, sna0, spa1, sna1);
            if (dy > 0) bodyA((dy-1)*9 + 8,   qa, w1, mp1, spb0, snb0, spb1, snb1);
        }

        // ---- Phase B: filter_grad = regw*w + lcv(mapped, rf) @ lr_w + lr_b ----
        auto bodyB = [&](int k, const float4* q, const float* mp, float* fg) {
            float ck = dot32q(mp, q) * (1.f / 32.f);
            const float* lr = lrw_p + k * 32;    // wave-uniform -> s_load
#pragma unroll
            for (int c = 0; c < 32; ++c) fg[c] += ck * lr[c];
        };
#pragma unroll
        for (int c = 0; c < 32; ++c) {
            fg0[c] = s_bias[32 + c] + regw * w0[c];
            fg1[c] = s_bias[32 + c] + regw * w1[c];
        }
#pragma unroll 1
        for (int dy = 0; dy < 10; ++dy) {
            const int rowbase = (ty2 + dy) * TWXc + tx;
            float4 qa[8], qb[8];
            LOADQ(qa, 0);
#pragma unroll 1
            for (int j = 0; j < 8; j += 2) {
                LOADQ(qb, j + 1);
                if (dy < 9) bodyB(dy*9 + j,       qa, mp0, fg0);
                if (dy > 0) bodyB((dy-1)*9 + j,   qa, mp1, fg1);
                LOADQ(qa, j + 2);
                if (dy < 9) bodyB(dy*9 + j+1,     qb, mp0, fg0);
                if (dy > 0) bodyB((dy-1)*9 + j+1, qb, mp1, fg1);
            }
            if (dy < 9) bodyB(dy*9 + 8,       qa, mp0, fg0);
            if (dy > 0) bodyB((dy-1)*9 + 8,   qa, mp1, fg1);
        }

        // ---- Phase C: alpha = sum(fg^2)/sum((dact*lcv(fg,rf))^2); w += alpha*step*fg ----
        auto bodyC = [&](int k, const float4* q, const float* fg,
                         unsigned long long sp0, unsigned long long sn0,
                         unsigned int sp1, unsigned int sn1, float& den) {
            float c3 = dot32q(fg, q) * (1.f / 32.f);
            bool bp = (k < 64) ? (((sp0 >> k) & 1ull) != 0) : (((sp1 >> (k - 64)) & 1u) != 0);
            bool bn = (k < 64) ? (((sn0 >> k) & 1ull) != 0) : (((sn1 >> (k - 64)) & 1u) != 0);
            float sg = bp ? 1.f : (bn ? -1.f : 0.f);
            float4 kp = s_kp[k];
            float dact = kp.x * sg + kp.y;
            float s3 = dact * c3;
            den += s3 * s3;
        };
        float num0 = 0.f, num1 = 0.f;
#pragma unroll
        for (int c = 0; c < 32; ++c) { num0 += fg0[c] * fg0[c]; num1 += fg1[c] * fg1[c]; }
        float den0 = 0.f, den1 = 0.f;
#pragma unroll 1
        for (int dy = 0; dy < 10; ++dy) {
            const int rowbase = (ty2 + dy) * TWXc + tx;
            float4 qa[8], qb[8];
            LOADQ(qa, 0);
#pragma unroll 1
            for (int j = 0; j < 8; j += 2) {
                LOADQ(qb, j + 1);
                if (dy < 9) bodyC(dy*9 + j,       qa, fg0, spa0, sna0, spa1, sna1, den0);
                if (dy > 0) bodyC((dy-1)*9 + j,   qa, fg1, spb0, snb0, spb1, snb1, den1);
                LOADQ(qa, j + 2);
                if (dy < 9) bodyC(dy*9 + j+1,     qb, fg0, spa0, sna0, spa1, sna1, den0);
                if (dy > 0) bodyC((dy-1)*9 + j+1, qb, fg1, spb0, snb0, spb1, snb1, den1);
            }
            if (dy < 9) bodyC(dy*9 + 8,       qa, fg0, spa0, sna0, spa1, sna1, den0);
            if (dy > 0) bodyC((dy-1)*9 + 8,   qa, fg1, spb0, snb0, spb1, snb1, den1);
        }
        float as0 = (num0 / den0) * step;
        float as1 = (num1 / den1) * step;
#pragma unroll
        for (int c = 0; c < 32; ++c) { w0[c] += as0 * fg0[c]; w1[c] += as1 * fg1[c]; }
    }
#undef LOADQ

    // ---- f32 output, coalesced float4 stores (two rows) ----
    float* o0 = out + (((size_t)bb * H_ + (by + ty2)) * W_ + (bx + tx)) * 32;
    float* o1 = o0 + (size_t)W_ * 32;
#pragma unroll
    for (int u = 0; u < 8; ++u) {
        *(float4*)(o0 + u * 4) = make_float4(w0[4*u+0], w0[4*u+1], w0[4*u+2], w0[4*u+3]);
        *(float4*)(o1 + u * 4) = make_float4(w1[4*u+0], w1[4*u+1], w1[4*u+2], w1[4*u+3]);
    }
}

// ============================================================================
// P=1 fallback kernel (unchanged) — used only if the 139,792 B dynamic-LDS
// opt-in is unavailable.
// ============================================================================
template<int TSX, int TSY, int NTH>
__global__ void __launch_bounds__(NTH)
gocor(const float* __restrict__ rf_g,
      const float* __restrict__ beta_p, const float* __restrict__ tw_p,
      const float* __restrict__ sw_p,  const float* __restrict__ mw_p,
      const float* __restrict__ mrw_p, const float* __restrict__ mrb_p,
      const float* __restrict__ lrw_p, const float* __restrict__ lrb_p,
      const float* __restrict__ wreg_p, const float* __restrict__ lsl_p,
      float* __restrict__ out)
{
    constexpr int TWXc = TSX + 8, TWYc = TSY + 8, NPXc = TWXc * TWYc;
    extern __shared__ float4 smem[];
    float4* s_rf  = smem;
    float4* s_kp  = smem + NPXc * PXF4;
    float*  s_bias = (float*)(s_kp + 81);

    const int tid = threadIdx.x;
    const int tx = tid % TSX, ty = tid / TSX;
    const int bx = blockIdx.x * TSX, by = blockIdx.y * TSY, bb = blockIdx.z;
    const float* rfb = rf_g + (size_t)bb * H_ * W_ * 32;

    for (int idx = tid; idx < NPXc * 8; idx += NTH) {
        int u = idx & 7, p = idx >> 3;
        int ly = p / TWXc, lx = p - ly * TWXc;
        int gy = by + ly - 4, gx = bx + lx - 4;
        float4 v = make_float4(0.f, 0.f, 0.f, 0.f);
        if (gy >= 0 && gy < H_ && gx >= 0 && gx < W_)
            v = *(const float4*)(rfb + ((size_t)(gy * W_ + gx)) * 32 + u * 4);
        s_rf[p * PXF4 + u] = v;
    }

    if (tid < 81) {
        int i = tid / 9, j = tid % 9;
        float di = (float)(i - 4), dj = (float)(j - 4);
        float dist = sqrtf(di * di + dj * dj);
        float y = 0.f, vp = 0.f, m = 0.f;
        for (int b = 0; b < 10; ++b) {
            float bd = 2.f * dist - (float)b;
            float val;
            if (i < 8) val = fmaxf(0.f, 1.f - fabsf(bd));
            else       val = fminf(1.f, fmaxf(0.f, 1.f + bd));
            y  += val * tw_p[b];
            vp += val * sw_p[b];
            m  += val * mw_p[b];
        }
        float wm = 1.f / (1.f + expf(-m));
        s_kp[tid] = make_float4(vp * 0.5f * (1.f - wm),
                                vp * 0.5f * (1.f + wm),
                                vp * y, 0.f);
    }
    if (tid < 32)      s_bias[tid]      = mrb_p[tid];
    else if (tid < 64) s_bias[tid]      = lrb_p[tid - 32];

    float beta = beta_p[0];
    float wr   = wreg_p[0];
    float regw = fmaxf(wr * wr, (1e-5f * 1e-5f) / (32.f * 32.f));
    float step = expf(lsl_p[0]);

    __syncthreads();

    float w[32];
    {
        const float4* r = &s_rf[(((ty + 4) * TWXc) + (tx + 4)) * PXF4];
#pragma unroll
        for (int u = 0; u < 8; ++u) {
            float4 q = r[u];
            w[4*u+0] = q.x; w[4*u+1] = q.y; w[4*u+2] = q.z; w[4*u+3] = q.w;
        }
        float msq = 0.f;
#pragma unroll
        for (int c = 0; c < 32; ++c) msq += w[c] * w[c];
        float inv = beta / (msq * (1.f / 32.f) + 1e-6f);
#pragma unroll
        for (int c = 0; c < 32; ++c) w[c] *= inv;
    }

    float mp[32], fg[32];

    for (int it = 0; it < 3; ++it) {
        unsigned long long sp0 = 0ull, sn0 = 0ull;
        unsigned int sp1 = 0u, sn1 = 0u;
#pragma unroll
        for (int c = 0; c < 32; ++c) mp[c] = s_bias[c];
        for (int i = 0; i < 9; ++i) {
            int rowbase = (ty + i) * TWXc + tx;
            for (int j = 0; j < 9; ++j) {
                int k = i * 9 + j;
                const float4* r = &s_rf[(rowbase + j) * PXF4];
                float ck = dot32f(w, r) * (1.f / 32.f);
                if (ck > 0.f)      { if (k < 64) sp0 |= 1ull << k; else sp1 |= 1u << (k - 64); }
                else if (ck < 0.f) { if (k < 64) sn0 |= 1ull << k; else sn1 |= 1u << (k - 64); }
                float4 kp = s_kp[k];
                float sg = (ck > 0.f) ? 1.f : ((ck < 0.f) ? -1.f : 0.f);
                float act  = kp.x * fabsf(ck) + kp.y * ck;
                float res  = act - kp.z;
                float dact = kp.x * sg + kp.y;
                float s = dact * res;
                const float* mr = mrw_p + k * 32;
#pragma unroll
                for (int c = 0; c < 32; ++c) mp[c] += s * mr[c];
            }
        }

#pragma unroll
        for (int c = 0; c < 32; ++c) fg[c] = s_bias[32 + c] + regw * w[c];
        for (int i = 0; i < 9; ++i) {
            int rowbase = (ty + i) * TWXc + tx;
            for (int j = 0; j < 9; ++j) {
                int k = i * 9 + j;
                const float4* r = &s_rf[(rowbase + j) * PXF4];
                float ck = dot32f(mp, r) * (1.f / 32.f);
                const float* lr = lrw_p + k * 32;
#pragma unroll
                for (int c = 0; c < 32; ++c) fg[c] += ck * lr[c];
            }
        }

        float num = 0.f;
#pragma unroll
        for (int c = 0; c < 32; ++c) num += fg[c] * fg[c];
        float den = 0.f;
        for (int i = 0; i < 9; ++i) {
            int rowbase = (ty + i) * TWXc + tx;
            for (int j = 0; j < 9; ++j) {
                int k = i * 9 + j;
                const float4* r = &s_rf[(rowbase + j) * PXF4];
                float c3 = dot32f(fg, r) * (1.f / 32.f);
                bool bp = (k < 64) ? ((sp0 >> k) & 1ull) : ((sp1 >> (k - 64)) & 1u);
                bool bn = (k < 64) ? ((sn0 >> k) & 1ull) : ((sn1 >> (k - 64)) & 1u);
                float sg = bp ? 1.f : (bn ? -1.f : 0.f);
                float4 kp = s_kp[k];
                float dact = kp.x * sg + kp.y;
                float s3 = dact * c3;
                den += s3 * s3;
            }
        }
        float as = (num / den) * step;
#pragma unroll
        for (int c = 0; c < 32; ++c) w[c] += as * fg[c];
    }

    float* o = out + (((size_t)bb * H_ + (by + ty)) * W_ + (bx + tx)) * 32;
#pragma unroll
    for (int u = 0; u < 8; ++u)
        *(float4*)(o + u * 4) = make_float4(w[4*u+0], w[4*u+1], w[4*u+2], w[4*u+3]);
}

// ---- LDS sizes ----
// big (P=2): 32x16 owned -> 40x24 px tile -> (960*9 + 81 + 16) float4 = 139,792 B (1 block/CU, 4 waves)
// small (P=1 fallback): 16x8 tile -> 24x16 px -> 56,848 B
static const size_t BIG_SHM   = (size_t)(40 * 24 * PXF4 + 81 + 16) * 16;
static const size_t SMALL_SHM = (size_t)(24 * 16 * PXF4 + 81 + 16) * 16;

static bool query_big_path() {
    // Runs once, on the first (uncaptured, correctness) call. No stream ops.
    int dev = 0;
    if (hipGetDevice(&dev) != hipSuccess) return false;
    hipFuncSetAttribute(reinterpret_cast<const void*>(&gocor2<32, 8, 256>),
                        hipFuncAttributeMaxDynamicSharedMemorySize, (int)BIG_SHM);
    int maxShm = 0;
    if (hipDeviceGetAttribute(&maxShm, hipDeviceAttributeMaxSharedMemoryPerBlock, dev) == hipSuccess &&
        (size_t)maxShm >= BIG_SHM)
        return true;
    hipFuncAttributes fa;
    if (hipFuncGetAttributes(&fa, reinterpret_cast<const void*>(&gocor2<32, 8, 256>)) == hipSuccess &&
        (size_t)fa.maxDynamicSharedSizeBytes >= BIG_SHM)
        return true;
    return false;
}

extern "C" void kernel_launch(void* const* d_in, const int* in_sizes, int n_in,
                              void* d_out, int out_size, void* d_ws, size_t ws_size,
                              hipStream_t stream) {
    (void)d_ws; (void)ws_size; (void)in_sizes; (void)n_in; (void)out_size;
    static const bool use_big = query_big_path();   // resolved before graph capture

    const float* rf   = (const float*)d_in[0];
    const float* beta = (const float*)d_in[2];
    const float* tw   = (const float*)d_in[3];
    const float* sw   = (const float*)d_in[4];
    const float* mw   = (const float*)d_in[5];
    const float* mrw  = (const float*)d_in[6];
    const float* mrb  = (const float*)d_in[7];
    const float* lrw  = (const float*)d_in[8];
    const float* lrb  = (const float*)d_in[9];
    const float* wreg = (const float*)d_in[10];
    const float* lsl  = (const float*)d_in[11];
    float* o = (float*)d_out;

    if (use_big) {
        dim3 grid(W_ / 32, H_ / 16, B_);
        hipLaunchKernelGGL((gocor2<32, 8, 256>), grid, dim3(256), BIG_SHM, stream,
                           rf, beta, tw, sw, mw, mrw, mrb, lrw, lrb, wreg, lsl, o);
    } else {
        dim3 grid(W_ / 16, H_ / 8, B_);
        hipLaunchKernelGGL((gocor<16, 8, 128>), grid, dim3(128), SMALL_SHM, stream,
                           rf, beta, tw, sw, mw, mrw, mrb, lrw, lrb, wreg, lsl, o);
    }
}